// Round 8
// baseline (276.591 us; speedup 1.0000x reference)
//
#include <hip/hip_runtime.h>
#include <hip/hip_bf16.h>
#include <math.h>

#define THREADS 256
#define MTHREADS 512
typedef unsigned short ushortT;
typedef __attribute__((ext_vector_type(8))) short bf16x8;   // 8 bf16 = 4 VGPRs
typedef __attribute__((ext_vector_type(4))) float f32x4;

__device__ __forceinline__ void async16(const ushortT* g, ushortT* l) {
  __builtin_amdgcn_global_load_lds(
      (const __attribute__((address_space(1))) unsigned int*)g,
      (__attribute__((address_space(3))) unsigned int*)l, 16, 0, 0);
}

__device__ __forceinline__ ushortT f2bf(float f) {
  __hip_bfloat16 h = __float2bfloat16(f);
  return *reinterpret_cast<ushortT*>(&h);
}

// ---------------------------------------------------------------------------
// Kernel A: fused L2-norm + bf16 convert. One block per row (256 thr x float4).
// ---------------------------------------------------------------------------
__global__ __launch_bounds__(THREADS) void k_prep(const float* __restrict__ x,
                                                  ushortT* __restrict__ xn, int D) {
  __shared__ float red[4];
  const int row = blockIdx.x;
  const int tid = threadIdx.x;
  const int gid = row * (D / 4) + tid;
  const float4 v = reinterpret_cast<const float4*>(x)[gid];
  float s = v.x * v.x + v.y * v.y + v.z * v.z + v.w * v.w;
  #pragma unroll
  for (int off = 32; off; off >>= 1) s += __shfl_xor(s, off);
  if ((tid & 63) == 0) red[tid >> 6] = s;
  __syncthreads();
  const float tot = red[0] + red[1] + red[2] + red[3];
  const float rn = 1.0f / fmaxf(sqrtf(tot), 1e-12f);
  ushort4 o;
  o.x = f2bf(v.x * rn); o.y = f2bf(v.y * rn);
  o.z = f2bf(v.z * rn); o.w = f2bf(v.w * rn);
  reinterpret_cast<ushort4*>(xn)[gid] = o;
}

// ---------------------------------------------------------------------------
// Kernel B: triangular 128x128 bf16 MFMA tiles, 8 waves x (64x32) per block.
//
// R7 post-mortem: (256,3) was a no-op — occupancy buckets quantize at total
// regs {64,128,256} (m69); 80 VGPR + 64 AGPR acc = 144 -> 2-waves/SIMD
// bucket regardless of the hint. The 64-AGPR accumulator is the blocker.
// This version halves the per-wave tile: 8 waves (512 thr), acc 4x2 = 32
// AGPR, K-loop live set ~110 < 128 -> 4 waves/SIMD -> 16 waves/CU (2x TLP).
// Per-block MFMA work per K-step unchanged (8 waves x 8 MFMA).
//   wave w: rows wr=(w>>2)*64 .. +64, cols wc=(w&3)*32 .. +32
//   staging: wave w stages 16-row group w of A and of B (1+1 async16/iter)
//   orientation 1: 32 cols/wave -> wave pairs (w, w^1) merge (m,sp,sn) via
//     8KB LDS after the K-loop, even wave writes the 64-col half (w&3)>>1.
//   orientation 2: wave's 64 i-rows = one half already (half = w>>2).
// partial[(row*NB + cb)*2 + half] = {mp, sp, 0, sn} (unchanged semantics)
// ---------------------------------------------------------------------------
__global__ __launch_bounds__(MTHREADS, 4) void k_main_mfma(const ushortT* __restrict__ xn,
                                                           const int* __restrict__ tgt,
                                                           float4* __restrict__ partial,
                                                           int D, int nb) {
  __shared__ ushortT Asm[128 * 32];   // 8 KB
  __shared__ ushortT Bsm[128 * 32];   // 8 KB
  __shared__ float4 mrg[8][64];       // 8 KB (orientation-1 pair merge)

  const int tid = threadIdx.x;
  const int lane = tid & 63;
  const int w = tid >> 6;             // 0..7

  // --- triangular decode: b -> (bi, bj), bi <= bj
  const int b = blockIdx.x;
  int bi = (int)((2.f * nb + 1.f -
                  sqrtf((2.f * nb + 1.f) * (2.f * nb + 1.f) - 8.f * (float)b)) * 0.5f);
  while ((bi + 1) * (2 * nb - bi) / 2 <= b) ++bi;
  while (bi * (2 * nb - bi + 1) / 2 > b) --bi;
  const int bj = bi + (b - bi * (2 * nb - bi + 1) / 2);
  const bool isdiag = (bi == bj);

  const int i0 = bi * 128, j0 = bj * 128;
  const int wr = (w >> 2) * 64;       // row offset: 0 or 64
  const int wc = (w & 3) * 32;        // col offset: 0,32,64,96

  // --- staging: wave w stages 16-row group w of A and of B.
  const int sr = lane & 15, sc = lane >> 4;
  const ushortT* gA = xn + (size_t)(i0 + w * 16 + sr) * D + sc * 8;
  const ushortT* gB = xn + (size_t)(j0 + w * 16 + sr) * D + sc * 8;
  ushortT* lA = &Asm[w * 512];
  ushortT* lB = &Bsm[w * 512];

  const ushortT* Bbase = isdiag ? Asm : Bsm;
  const int aoff = ((w >> 2) * 4) * 512 + lane * 8;   // A groups (w>>2)*4 + mt
  const int boff = ((w & 3) * 2) * 512 + lane * 8;    // B groups (w&3)*2 + nt

  f32x4 acc[4][2];
  #pragma unroll
  for (int mt = 0; mt < 4; ++mt)
    #pragma unroll
    for (int nt = 0; nt < 2; ++nt)
      acc[mt][nt] = (f32x4){0.f, 0.f, 0.f, 0.f};

  const int kiters = D / 32;
  for (int kk = 0; kk < kiters; ++kk) {
    const size_t ko = (size_t)kk * 32;
    async16(gA + ko, lA);
    if (!isdiag) async16(gB + ko, lB);
    __syncthreads();
    bf16x8 afr[4];
    #pragma unroll
    for (int mt = 0; mt < 4; ++mt)
      afr[mt] = *reinterpret_cast<const bf16x8*>(&Asm[aoff + mt * 512]);
    bf16x8 bfr[2];
    #pragma unroll
    for (int nt = 0; nt < 2; ++nt)
      bfr[nt] = *reinterpret_cast<const bf16x8*>(&Bbase[boff + nt * 512]);
    #pragma unroll
    for (int mt = 0; mt < 4; ++mt)
      #pragma unroll
      for (int nt = 0; nt < 2; ++nt)
        acc[mt][nt] = __builtin_amdgcn_mfma_f32_16x16x32_bf16(afr[mt], bfr[nt], acc[mt][nt], 0, 0, 0);
    __syncthreads();
  }

  // --- epilogue. C/D layout: col = lane&15, row = (lane>>4)*4 + reg
  const int q = lane >> 4, c = lane & 15;
  int tj[2];
  #pragma unroll
  for (int nt = 0; nt < 2; ++nt) tj[nt] = tgt[j0 + wc + nt * 16 + c];
  int tir[16];
  #pragma unroll
  for (int mt = 0; mt < 4; ++mt) {
    const int4 t4 = *reinterpret_cast<const int4*>(tgt + i0 + wr + mt * 16 + q * 4);
    tir[mt * 4 + 0] = t4.x; tir[mt * 4 + 1] = t4.y;
    tir[mt * 4 + 2] = t4.z; tir[mt * 4 + 3] = t4.w;
  }

  // orientation 1: rows of bi block, this wave's 32 cols of bj block.
  // Per-wave (m, sp, sn) per row -> LDS; pair (w, w^1) merges to a 64-col half.
  #pragma unroll
  for (int mt = 0; mt < 4; ++mt) {
    #pragma unroll
    for (int reg = 0; reg < 4; ++reg) {
      const int i = i0 + wr + mt * 16 + q * 4 + reg;
      const int ti = tir[mt * 4 + reg];
      float m = -1e30f, sn = 0.f;
      float sel[2];
      #pragma unroll
      for (int nt = 0; nt < 2; ++nt) {
        const float s = acc[mt][nt][reg];
        const int j = j0 + wc + nt * 16 + c;
        const bool same = (tj[nt] == ti);
        const bool vpos = same && (j != i);
        const float lp = (fminf(s, 1.25f) - 1.25f) * fmaf(s, 64.f, -48.f);
        const float sv = vpos ? lp : -2e30f;
        sel[nt] = sv;
        m = fmaxf(m, sv);
        const float ln = (fmaxf(s, -0.25f) + 0.25f) * fmaf(s, 64.f, -16.f);
        const float en = __expf(ln);
        sn += same ? 0.f : en;
      }
      #pragma unroll
      for (int off = 1; off < 16; off <<= 1) m = fmaxf(m, __shfl_xor(m, off));
      float sp = 0.f;
      #pragma unroll
      for (int nt = 0; nt < 2; ++nt) sp += __expf(sel[nt] - m);
      #pragma unroll
      for (int off = 1; off < 16; off <<= 1) {
        sp += __shfl_xor(sp, off);
        sn += __shfl_xor(sn, off);
      }
      if (c == 0) {
        float4 o; o.x = m; o.y = sp; o.z = 0.f; o.w = sn;
        mrg[w][mt * 16 + q * 4 + reg] = o;
      }
    }
  }
  __syncthreads();
  if (!(w & 1)) {   // even wave merges itself with w+1; one row per lane
    const float4 a = mrg[w][lane];
    const float4 b2 = mrg[w + 1][lane];
    const float m = fmaxf(a.x, b2.x);
    const float sp = a.y * __expf(a.x - m) + b2.y * __expf(b2.x - m);
    const float sn = a.w + b2.w;
    float4 o; o.x = m; o.y = sp; o.z = 0.f; o.w = sn;
    partial[((size_t)(i0 + wr + lane) * nb + bj) * 2 + ((w & 3) >> 1)] = o;
  }

  // orientation 2: rows of bj block (this wave's 32), cols = wave's 64 i-rows
  // = one half (half = w>>2). Off-diagonal only. Two-pass, register-lean.
  if (!isdiag) {
    #pragma unroll
    for (int nt = 0; nt < 2; ++nt) {
      const int jt = tj[nt];
      const int jrow = j0 + wc + nt * 16 + c;
      float m = -1e30f, sn = 0.f;
      #pragma unroll
      for (int mt = 0; mt < 4; ++mt) {
        #pragma unroll
        for (int reg = 0; reg < 4; ++reg) {
          const float s = acc[mt][nt][reg];
          const bool same = (tir[mt * 4 + reg] == jt);  // j != i guaranteed off-diag
          const float lp = (fminf(s, 1.25f) - 1.25f) * fmaf(s, 64.f, -48.f);
          m = fmaxf(m, same ? lp : -2e30f);
          const float ln = (fmaxf(s, -0.25f) + 0.25f) * fmaf(s, 64.f, -16.f);
          const float en = __expf(ln);
          sn += same ? 0.f : en;
        }
      }
      m = fmaxf(m, __shfl_xor(m, 16));
      m = fmaxf(m, __shfl_xor(m, 32));
      float sp = 0.f;
      #pragma unroll
      for (int mt = 0; mt < 4; ++mt) {
        #pragma unroll
        for (int reg = 0; reg < 4; ++reg) {
          const float s = acc[mt][nt][reg];
          const bool same = (tir[mt * 4 + reg] == jt);
          const float lp = (fminf(s, 1.25f) - 1.25f) * fmaf(s, 64.f, -48.f);
          sp += __expf((same ? lp : -2e30f) - m);
        }
      }
      sp += __shfl_xor(sp, 16); sp += __shfl_xor(sp, 32);
      sn += __shfl_xor(sn, 16); sn += __shfl_xor(sn, 32);
      if (lane < 16) {
        float4 o; o.x = m; o.y = sp; o.z = 0.f; o.w = sn;
        partial[((size_t)jrow * nb + bi) * 2 + (w >> 2)] = o;
      }
    }
  }
}

// ---------------------------------------------------------------------------
// Kernel C: fold 128 partials per row -> row loss. One wave per row.
// ---------------------------------------------------------------------------
__global__ __launch_bounds__(THREADS) void k_reduce(const float4* __restrict__ partial,
                                                    float* __restrict__ row_loss) {
  const int lane = threadIdx.x & 63;
  const int row = blockIdx.x * 4 + (threadIdx.x >> 6);
  const float4 a = partial[(size_t)row * 128 + lane];
  const float4 b = partial[(size_t)row * 128 + 64 + lane];
  float mp = fmaxf(a.x, b.x);
  float sp = a.y * __expf(a.x - mp) + b.y * __expf(b.x - mp);
  float sn = a.w + b.w;
  #pragma unroll
  for (int off = 1; off < 64; off <<= 1) {
    const float m2 = __shfl_xor(mp, off), s2 = __shfl_xor(sp, off);
    const float nm = fmaxf(mp, m2);
    sp = sp * __expf(mp - nm) + s2 * __expf(m2 - nm);
    mp = nm;
    sn += __shfl_xor(sn, off);
  }
  if (lane == 0) {
    float loss = -1.0f;
    if (sp > 0.f && sn > 0.f) {
      const float z = mp + logf(sp) + logf(sn);
      loss = (z > 0.f) ? (z + log1pf(__expf(-z))) : log1pf(__expf(z));
    }
    row_loss[row] = loss;
  }
}

// ---------------------------------------------------------------------------
// Kernel D: masked mean over rows. One block.
// ---------------------------------------------------------------------------
__global__ __launch_bounds__(THREADS) void k_final(const float* __restrict__ row_loss,
                                                   float* __restrict__ out, int B) {
  __shared__ float ssum[4];
  __shared__ float scnt[4];
  const int tid = threadIdx.x;
  float sum = 0.f, cnt = 0.f;
  for (int i = tid; i < B; i += THREADS) {
    const float l = row_loss[i];
    if (l >= 0.f) { sum += l; cnt += 1.f; }
  }
  #pragma unroll
  for (int off = 32; off; off >>= 1) {
    sum += __shfl_xor(sum, off);
    cnt += __shfl_xor(cnt, off);
  }
  if ((tid & 63) == 0) { ssum[tid >> 6] = sum; scnt[tid >> 6] = cnt; }
  __syncthreads();
  if (tid == 0) {
    float ts = 0.f, tc = 0.f;
    #pragma unroll
    for (int w = 0; w < 4; ++w) { ts += ssum[w]; tc += scnt[w]; }
    out[0] = ts / fmaxf(tc, 1.f);
  }
}

// ---------------------------------------------------------------------------
extern "C" void kernel_launch(void* const* d_in, const int* in_sizes, int n_in,
                              void* d_out, int out_size, void* d_ws, size_t ws_size,
                              hipStream_t stream) {
  const float* x = (const float*)d_in[0];
  const int* tgt = (const int*)d_in[1];
  float* out = (float*)d_out;
  const int B = in_sizes[1];
  const int D = in_sizes[0] / B;
  const int nb = B / 128;

  ushortT* xn = (ushortT*)d_ws;                                   // B*D bf16 (16 MB)
  float4* partial = (float4*)((char*)d_ws + (size_t)B * D * 2);   // B*2*nb float4 (16 MB)
  float* row_loss = (float*)((char*)d_ws + (size_t)B * D * 2 + (size_t)B * 2 * nb * 16);

  k_prep<<<B, THREADS, 0, stream>>>(x, xn, D);
  k_main_mfma<<<nb * (nb + 1) / 2, MTHREADS, 0, stream>>>(xn, tgt, partial, D, nb);
  k_reduce<<<B / 4, THREADS, 0, stream>>>(partial, row_loss);
  k_final<<<1, THREADS, 0, stream>>>(row_loss, out, B);
}

// Round 9
// 244.005 us; speedup vs baseline: 1.1335x; 1.1335x over previous
//
#include <hip/hip_runtime.h>
#include <hip/hip_bf16.h>
#include <math.h>

#define THREADS 256
typedef unsigned short ushortT;
typedef __attribute__((ext_vector_type(8))) short bf16x8;   // 8 bf16 = 4 VGPRs
typedef __attribute__((ext_vector_type(4))) float f32x4;

__device__ __forceinline__ void async16(const ushortT* g, ushortT* l) {
  __builtin_amdgcn_global_load_lds(
      (const __attribute__((address_space(1))) unsigned int*)g,
      (__attribute__((address_space(3))) unsigned int*)l, 16, 0, 0);
}

__device__ __forceinline__ ushortT f2bf(float f) {
  __hip_bfloat16 h = __float2bfloat16(f);
  return *reinterpret_cast<ushortT*>(&h);
}

// ---------------------------------------------------------------------------
// Kernel A: fused L2-norm + bf16 convert. One block per row (256 thr x float4).
// ---------------------------------------------------------------------------
__global__ __launch_bounds__(THREADS) void k_prep(const float* __restrict__ x,
                                                  ushortT* __restrict__ xn, int D) {
  __shared__ float red[4];
  const int row = blockIdx.x;
  const int tid = threadIdx.x;
  const int gid = row * (D / 4) + tid;
  const float4 v = reinterpret_cast<const float4*>(x)[gid];
  float s = v.x * v.x + v.y * v.y + v.z * v.z + v.w * v.w;
  #pragma unroll
  for (int off = 32; off; off >>= 1) s += __shfl_xor(s, off);
  if ((tid & 63) == 0) red[tid >> 6] = s;
  __syncthreads();
  const float tot = red[0] + red[1] + red[2] + red[3];
  const float rn = 1.0f / fmaxf(sqrtf(tot), 1e-12f);
  ushort4 o;
  o.x = f2bf(v.x * rn); o.y = f2bf(v.y * rn);
  o.z = f2bf(v.z * rn); o.w = f2bf(v.w * rn);
  reinterpret_cast<ushort4*>(xn)[gid] = o;
}

// ---------------------------------------------------------------------------
// Kernel B: triangular 128x128 bf16 MFMA tiles + dual-orientation circle-loss
// epilogue. Block b -> (bi <= bj). Grid = nb(nb+1)/2 = 2080 blocks (nb=64).
//
// History: R0 BK=32 = 176us/397TF (local opt). R4 counted-vmcnt -8%. R5
// no-LDS -60%. R6 BK=128 -9% (16 outstanding loads, 64KB LDS, occ fell).
// R8 8-wave 64x32 -15% (halved MFMA/wave/iter). Lesson: the lever is MFMA-
// cycles per wave per barrier interval at unchanged acc/occupancy.
//
// This round: BK=64 (untried midpoint). 16 K-iters; per iter each wave does
// 2 sub-steps x 16 MFMA = 32 MFMA (608 cyc) against one barrier drain;
// 8 async16/wave/iter (4 on diag); LDS 2x16KB = 32KB -> 2 blocks = 64KB.
// LDS layout: [8 groups][2 ksub][512], group g = 16 rows, ksub = 32-k slice,
// fragment-read order (lane*16B contiguous) — same map as R0 per ksub.
// partial[(row*NB + cb)*2 + half] = {mp, sp, 0, sn}
// ---------------------------------------------------------------------------
__global__ __launch_bounds__(THREADS, 2) void k_main_mfma(const ushortT* __restrict__ xn,
                                                          const int* __restrict__ tgt,
                                                          float4* __restrict__ partial,
                                                          int D, int nb) {
  __shared__ ushortT Asm[128 * 64];  // 16 KB
  __shared__ ushortT Bsm[128 * 64];  // 16 KB

  const int tid = threadIdx.x;
  const int lane = tid & 63;
  const int w = tid >> 6;

  // --- triangular decode: b -> (bi, bj), bi <= bj
  const int b = blockIdx.x;
  int bi = (int)((2.f * nb + 1.f -
                  sqrtf((2.f * nb + 1.f) * (2.f * nb + 1.f) - 8.f * (float)b)) * 0.5f);
  while ((bi + 1) * (2 * nb - bi) / 2 <= b) ++bi;
  while (bi * (2 * nb - bi + 1) / 2 > b) --bi;
  const int bj = bi + (b - bi * (2 * nb - bi + 1) / 2);
  const bool isdiag = (bi == bj);

  const int i0 = bi * 128, j0 = bj * 128;
  const int wr = (w >> 1) * 64, wc = (w & 1) * 64;

  // --- staging: lane fetches (row = lane&15, chunk = lane>>4) of each 16x32
  // subtile; wave w stages groups w and w+4 of A and B, ksub 0 and 1.
  const int sr = lane & 15, sc = lane >> 4;
  const ushortT* gA0 = xn + (size_t)(i0 + w * 16 + sr) * D + sc * 8;
  const ushortT* gA1 = gA0 + (size_t)64 * D;
  const ushortT* gB0 = xn + (size_t)(j0 + w * 16 + sr) * D + sc * 8;
  const ushortT* gB1 = gB0 + (size_t)64 * D;
  ushortT* lA0 = &Asm[w * 1024];
  ushortT* lA1 = &Asm[(w + 4) * 1024];
  ushortT* lB0 = &Bsm[w * 1024];
  ushortT* lB1 = &Bsm[(w + 4) * 1024];

  const ushortT* Bbase = isdiag ? Asm : Bsm;
  const int aoff = ((w >> 1) * 4) * 1024 + lane * 8;   // ushort index
  const int boff = ((w & 1) * 4) * 1024 + lane * 8;

  f32x4 acc[4][4];
  #pragma unroll
  for (int mt = 0; mt < 4; ++mt)
    #pragma unroll
    for (int nt = 0; nt < 4; ++nt)
      acc[mt][nt] = (f32x4){0.f, 0.f, 0.f, 0.f};

  const int kiters = D / 64;   // 16
  for (int kk = 0; kk < kiters; ++kk) {
    const size_t ko = (size_t)kk * 64;
    async16(gA0 + ko, lA0);
    async16(gA0 + ko + 32, lA0 + 512);
    async16(gA1 + ko, lA1);
    async16(gA1 + ko + 32, lA1 + 512);
    if (!isdiag) {
      async16(gB0 + ko, lB0);
      async16(gB0 + ko + 32, lB0 + 512);
      async16(gB1 + ko, lB1);
      async16(gB1 + ko + 32, lB1 + 512);
    }
    __syncthreads();
    #pragma unroll
    for (int s = 0; s < 2; ++s) {
      bf16x8 afr[4];
      #pragma unroll
      for (int mt = 0; mt < 4; ++mt)
        afr[mt] = *reinterpret_cast<const bf16x8*>(&Asm[aoff + mt * 1024 + s * 512]);
      bf16x8 b0 = *reinterpret_cast<const bf16x8*>(&Bbase[boff + s * 512]);
      bf16x8 b1 = *reinterpret_cast<const bf16x8*>(&Bbase[boff + 1024 + s * 512]);
      #pragma unroll
      for (int mt = 0; mt < 4; ++mt)
        acc[mt][0] = __builtin_amdgcn_mfma_f32_16x16x32_bf16(afr[mt], b0, acc[mt][0], 0, 0, 0);
      #pragma unroll
      for (int mt = 0; mt < 4; ++mt)
        acc[mt][1] = __builtin_amdgcn_mfma_f32_16x16x32_bf16(afr[mt], b1, acc[mt][1], 0, 0, 0);
      b0 = *reinterpret_cast<const bf16x8*>(&Bbase[boff + 2 * 1024 + s * 512]);
      b1 = *reinterpret_cast<const bf16x8*>(&Bbase[boff + 3 * 1024 + s * 512]);
      #pragma unroll
      for (int mt = 0; mt < 4; ++mt)
        acc[mt][2] = __builtin_amdgcn_mfma_f32_16x16x32_bf16(afr[mt], b0, acc[mt][2], 0, 0, 0);
      #pragma unroll
      for (int mt = 0; mt < 4; ++mt)
        acc[mt][3] = __builtin_amdgcn_mfma_f32_16x16x32_bf16(afr[mt], b1, acc[mt][3], 0, 0, 0);
    }
    __syncthreads();
  }

  // --- epilogue. C/D layout: col = lane&15, row = (lane>>4)*4 + reg
  const int q = lane >> 4, c = lane & 15;
  int tj[4];
  #pragma unroll
  for (int nt = 0; nt < 4; ++nt) tj[nt] = tgt[j0 + wc + nt * 16 + c];
  int tir[16];
  #pragma unroll
  for (int mt = 0; mt < 4; ++mt) {
    const int4 t4 = *reinterpret_cast<const int4*>(tgt + i0 + wr + mt * 16 + q * 4);
    tir[mt * 4 + 0] = t4.x; tir[mt * 4 + 1] = t4.y;
    tir[mt * 4 + 2] = t4.z; tir[mt * 4 + 3] = t4.w;
  }

  // orientation 1: rows of bi block, cols of bj block
  #pragma unroll
  for (int mt = 0; mt < 4; ++mt) {
    #pragma unroll
    for (int reg = 0; reg < 4; ++reg) {
      const int i = i0 + wr + mt * 16 + q * 4 + reg;
      const int ti = tir[mt * 4 + reg];
      float m = -1e30f, sn = 0.f;
      float sel[4];
      #pragma unroll
      for (int nt = 0; nt < 4; ++nt) {
        const float s = acc[mt][nt][reg];
        const int j = j0 + wc + nt * 16 + c;
        const bool same = (tj[nt] == ti);
        const bool vpos = same && (j != i);
        const float lp = (fminf(s, 1.25f) - 1.25f) * fmaf(s, 64.f, -48.f);
        const float sv = vpos ? lp : -2e30f;
        sel[nt] = sv;
        m = fmaxf(m, sv);
        const float ln = (fmaxf(s, -0.25f) + 0.25f) * fmaf(s, 64.f, -16.f);
        const float en = __expf(ln);
        sn += same ? 0.f : en;
      }
      #pragma unroll
      for (int off = 1; off < 16; off <<= 1) m = fmaxf(m, __shfl_xor(m, off));
      float sp = 0.f;
      #pragma unroll
      for (int nt = 0; nt < 4; ++nt) sp += __expf(sel[nt] - m);
      #pragma unroll
      for (int off = 1; off < 16; off <<= 1) {
        sp += __shfl_xor(sp, off);
        sn += __shfl_xor(sn, off);
      }
      if (c == 0) {
        float4 o; o.x = m; o.y = sp; o.z = 0.f; o.w = sn;
        partial[((size_t)i * nb + bj) * 2 + (w & 1)] = o;
      }
    }
  }

  // orientation 2: rows of bj block, cols of bi block (off-diagonal only).
  // Two-pass, register-lean: pass 1 finds max (sentinel inline) + neg sum,
  // pass 2 recomputes lp and accumulates exp(lp - m).
  if (!isdiag) {
    #pragma unroll
    for (int nt = 0; nt < 4; ++nt) {
      const int jt = tj[nt];
      const int jrow = j0 + wc + nt * 16 + c;
      float m = -1e30f, sn = 0.f;
      #pragma unroll
      for (int mt = 0; mt < 4; ++mt) {
        #pragma unroll
        for (int reg = 0; reg < 4; ++reg) {
          const float s = acc[mt][nt][reg];
          const bool same = (tir[mt * 4 + reg] == jt);  // j != i guaranteed off-diag
          const float lp = (fminf(s, 1.25f) - 1.25f) * fmaf(s, 64.f, -48.f);
          m = fmaxf(m, same ? lp : -2e30f);
          const float ln = (fmaxf(s, -0.25f) + 0.25f) * fmaf(s, 64.f, -16.f);
          const float en = __expf(ln);
          sn += same ? 0.f : en;
        }
      }
      m = fmaxf(m, __shfl_xor(m, 16));
      m = fmaxf(m, __shfl_xor(m, 32));
      float sp = 0.f;
      #pragma unroll
      for (int mt = 0; mt < 4; ++mt) {
        #pragma unroll
        for (int reg = 0; reg < 4; ++reg) {
          const float s = acc[mt][nt][reg];
          const bool same = (tir[mt * 4 + reg] == jt);
          const float lp = (fminf(s, 1.25f) - 1.25f) * fmaf(s, 64.f, -48.f);
          sp += __expf((same ? lp : -2e30f) - m);
        }
      }
      sp += __shfl_xor(sp, 16); sp += __shfl_xor(sp, 32);
      sn += __shfl_xor(sn, 16); sn += __shfl_xor(sn, 32);
      if (lane < 16) {
        float4 o; o.x = m; o.y = sp; o.z = 0.f; o.w = sn;
        partial[((size_t)jrow * nb + bi) * 2 + (w >> 1)] = o;
      }
    }
  }
}

// ---------------------------------------------------------------------------
// Kernel C: fold 128 partials per row -> row loss. One wave per row.
// ---------------------------------------------------------------------------
__global__ __launch_bounds__(THREADS) void k_reduce(const float4* __restrict__ partial,
                                                    float* __restrict__ row_loss) {
  const int lane = threadIdx.x & 63;
  const int row = blockIdx.x * 4 + (threadIdx.x >> 6);
  const float4 a = partial[(size_t)row * 128 + lane];
  const float4 b = partial[(size_t)row * 128 + 64 + lane];
  float mp = fmaxf(a.x, b.x);
  float sp = a.y * __expf(a.x - mp) + b.y * __expf(b.x - mp);
  float sn = a.w + b.w;
  #pragma unroll
  for (int off = 1; off < 64; off <<= 1) {
    const float m2 = __shfl_xor(mp, off), s2 = __shfl_xor(sp, off);
    const float nm = fmaxf(mp, m2);
    sp = sp * __expf(mp - nm) + s2 * __expf(m2 - nm);
    mp = nm;
    sn += __shfl_xor(sn, off);
  }
  if (lane == 0) {
    float loss = -1.0f;
    if (sp > 0.f && sn > 0.f) {
      const float z = mp + logf(sp) + logf(sn);
      loss = (z > 0.f) ? (z + log1pf(__expf(-z))) : log1pf(__expf(z));
    }
    row_loss[row] = loss;
  }
}

// ---------------------------------------------------------------------------
// Kernel D: masked mean over rows. One block.
// ---------------------------------------------------------------------------
__global__ __launch_bounds__(THREADS) void k_final(const float* __restrict__ row_loss,
                                                   float* __restrict__ out, int B) {
  __shared__ float ssum[4];
  __shared__ float scnt[4];
  const int tid = threadIdx.x;
  float sum = 0.f, cnt = 0.f;
  for (int i = tid; i < B; i += THREADS) {
    const float l = row_loss[i];
    if (l >= 0.f) { sum += l; cnt += 1.f; }
  }
  #pragma unroll
  for (int off = 32; off; off >>= 1) {
    sum += __shfl_xor(sum, off);
    cnt += __shfl_xor(cnt, off);
  }
  if ((tid & 63) == 0) { ssum[tid >> 6] = sum; scnt[tid >> 6] = cnt; }
  __syncthreads();
  if (tid == 0) {
    float ts = 0.f, tc = 0.f;
    #pragma unroll
    for (int w = 0; w < 4; ++w) { ts += ssum[w]; tc += scnt[w]; }
    out[0] = ts / fmaxf(tc, 1.f);
  }
}

// ---------------------------------------------------------------------------
extern "C" void kernel_launch(void* const* d_in, const int* in_sizes, int n_in,
                              void* d_out, int out_size, void* d_ws, size_t ws_size,
                              hipStream_t stream) {
  const float* x = (const float*)d_in[0];
  const int* tgt = (const int*)d_in[1];
  float* out = (float*)d_out;
  const int B = in_sizes[1];
  const int D = in_sizes[0] / B;
  const int nb = B / 128;

  ushortT* xn = (ushortT*)d_ws;                                   // B*D bf16 (16 MB)
  float4* partial = (float4*)((char*)d_ws + (size_t)B * D * 2);   // B*2*nb float4 (16 MB)
  float* row_loss = (float*)((char*)d_ws + (size_t)B * D * 2 + (size_t)B * 2 * nb * 16);

  k_prep<<<B, THREADS, 0, stream>>>(x, xn, D);
  k_main_mfma<<<nb * (nb + 1) / 2, THREADS, 0, stream>>>(xn, tgt, partial, D, nb);
  k_reduce<<<B / 4, THREADS, 0, stream>>>(partial, row_loss);
  k_final<<<1, THREADS, 0, stream>>>(row_loss, out, B);
}